// Round 19
// baseline (164.444 us; speedup 1.0000x reference)
//
#include <hip/hip_runtime.h>
#include <math.h>

#define B_ 16
#define NAV_ 36
#define H_ 120
#define W_ 160
#define HID_ 512
#define PLANES (B_*NAV_)          // 576
#define PLANE_PX (H_*W_)          // 19200
#define CANVAS_H 360
#define CANVAS_W 1920
#define CANVAS_PX (CANVAS_H*CANVAS_W)  // 691200

// fused f16 LDS tiling: 12 output rows/band, 5 bands per block (R14 geometry).
// ROWB = 392 B (98 dwords; 98 mod 32 = 2) -> adjacent LDS rows hit disjoint
// bank groups; only the free 2-way (s vs s+8) aliasing remains.  ROWB=352
// (88 dwords, mod 32 = 24) stacked rows onto the same banks (5.5M conflict
// cycles/dispatch).
#define OUT_H 12
#define IN_ROWS 20
#define TD_ROWS 16
#define OBJ_ROWS 16
#define ROWB 392
#define INCH (IN_ROWS*ROWB)
#define NSLOT (2*IN_ROWS*44 + OBJ_ROWS*44)   // 2464
#define SPT 10

// workspace offsets (in floats); canvas region is used as f16 (half space)
#define WS_NAV    0
#define WS_FATT   576
#define WS_KERN   640
#define WS_TD     29440
#define WS_CANVAS (WS_TD + PLANES*PLANE_PX)
#define WS_POOL1  (WS_CANVAS + B_*CANVAS_PX)
#define WS_VF     (WS_POOL1 + B_*2*19*89)

typedef unsigned int u32;
typedef unsigned short u16;
typedef _Float16 h2_t __attribute__((ext_vector_type(2)));
typedef float float4a __attribute__((ext_vector_type(4), aligned(4)));

__device__ __forceinline__ float sigmoidf_(float x) { return 1.f / (1.f + expf(-x)); }

__device__ __forceinline__ u32 pkh(float a, float b) {
    return __builtin_bit_cast(u32, __builtin_amdgcn_cvt_pkrtz(a, b));
}
__device__ __forceinline__ float h2f(u16 h) {
    _Float16 v = __builtin_bit_cast(_Float16, h);
    return (float)v;
}
__device__ __forceinline__ float dot2h(u32 a, u32 b, float c) {
#if __has_builtin(__builtin_amdgcn_fdot2)
    return __builtin_amdgcn_fdot2(__builtin_bit_cast(h2_t, a),
                                  __builtin_bit_cast(h2_t, b), c, false);
#else
    float r;
    asm("v_dot2_f32_f16 %0, %1, %2, %3" : "=v"(r) : "v"(a), "v"(b), "v"(c));
    return r;
#endif
}

// 8-px, 2-channel, 5x5 conv via dot2 (odd pairs via alignbit).
__device__ __forceinline__ void conv8(const unsigned char* b0, const unsigned char* b1,
                                      const u32* ew, float* acc)
{
    #pragma unroll
    for (int ky = 0; ky < 5; ++ky) {
        const int off = ky*ROWB;
        int4 qa = *(const int4*)(b0 + off);
        int2 qb = *(const int2*)(b0 + off + 16);
        int4 ra = *(const int4*)(b1 + off);
        int2 rb = *(const int2*)(b1 + off + 16);
        u32 P[6] = {(u32)qa.x,(u32)qa.y,(u32)qa.z,(u32)qa.w,(u32)qb.x,(u32)qb.y};
        u32 Q[6] = {(u32)ra.x,(u32)ra.y,(u32)ra.z,(u32)ra.w,(u32)rb.x,(u32)rb.y};
        const u32 e0 = ew[ky*3+0], e1 = ew[ky*3+1], e2 = ew[ky*3+2];
        const u32 f0 = ew[15+ky*3+0], f1 = ew[15+ky*3+1], f2 = ew[15+ky*3+2];
        const u32 o0 = e0 << 16;
        const u32 o1 = __builtin_amdgcn_alignbit(e1, e0, 16);
        const u32 o2 = __builtin_amdgcn_alignbit(e2, e1, 16);
        const u32 g0 = f0 << 16;
        const u32 g1 = __builtin_amdgcn_alignbit(f1, f0, 16);
        const u32 g2 = __builtin_amdgcn_alignbit(f2, f1, 16);
        #pragma unroll
        for (int m = 0; m < 4; ++m) {
            acc[2*m]   = dot2h(e0, P[m], dot2h(e1, P[m+1], dot2h(e2, P[m+2], acc[2*m])));
            acc[2*m+1] = dot2h(o0, P[m], dot2h(o1, P[m+1], dot2h(o2, P[m+2], acc[2*m+1])));
            acc[2*m]   = dot2h(f0, Q[m], dot2h(f1, Q[m+1], dot2h(f2, Q[m+2], acc[2*m])));
            acc[2*m+1] = dot2h(g0, Q[m], dot2h(g1, Q[m+1], dot2h(g2, Q[m+2], acc[2*m+1])));
        }
    }
}

#define LOAD_EW(EW, SW)                                                        \
    {                                                                          \
        _Pragma("unroll")                                                      \
        for (int q = 0; q < 7; ++q) {                                          \
            int4 t_ = ((const int4*)(SW))[q];                                  \
            EW[4*q]=(u32)t_.x; EW[4*q+1]=(u32)t_.y; EW[4*q+2]=(u32)t_.z; EW[4*q+3]=(u32)t_.w; \
        }                                                                      \
        int2 t_ = ((const int2*)(SW))[14];                                     \
        EW[28]=(u32)t_.x; EW[29]=(u32)t_.y;                                    \
    }

// ---------------------------------------------------------------------------
// Kernel 0: tiny precompute.  grid 16, 256 threads.
// ---------------------------------------------------------------------------
__global__ __launch_bounds__(256)
void k_pre(const float* __restrict__ wctx, const float* __restrict__ dw1,
           const float* __restrict__ db1, const float* __restrict__ dw2,
           const float* __restrict__ db2, const float* __restrict__ dynf,
           const float* __restrict__ numnav, float* __restrict__ ws)
{
    const int tid = threadIdx.x;
    const int b = blockIdx.x;
    __shared__ float sh[128];
    __shared__ float sred[8];
    __shared__ float nv[36];
    __shared__ float nms[2];
    if (tid < 128) {
        float acc = db1[tid];
        for (int k = 0; k < HID_; ++k) acc += wctx[b*HID_ + k] * dw1[k*128 + tid];
        sh[tid] = fmaxf(acc, 0.f);
    }
    __syncthreads();
    if (tid < 4) {
        float acc = db2[tid];
        for (int j = 0; j < 128; ++j) acc += sh[j] * dw2[j*4 + tid];
        sred[tid] = acc;
    }
    __syncthreads();
    if (tid == 0) {
        float m = fmaxf(fmaxf(sred[0], sred[1]), fmaxf(sred[2], sred[3]));
        float e0 = expf(sred[0]-m), e1 = expf(sred[1]-m), e2 = expf(sred[2]-m), e3 = expf(sred[3]-m);
        float s = e0+e1+e2+e3;
        sred[4] = e0/s; sred[5] = e1/s; sred[6] = e2/s; sred[7] = e3/s;
        ws[WS_FATT + b*4+0] = sred[4]; ws[WS_FATT + b*4+1] = sred[5];
        ws[WS_FATT + b*4+2] = sred[6]; ws[WS_FATT + b*4+3] = sred[7];
    }
    __syncthreads();
    {
        const float fa0 = sred[4], fa1 = sred[5], fa2 = sred[6], fa3 = sred[7];
        for (int e = tid; e < 1800; e += 256) {
            float v = fa0*dynf[e] + fa1*dynf[1800+e] + fa2*dynf[3600+e] + fa3*dynf[5400+e];
            ws[WS_KERN + b*1800 + e] = v;
        }
    }
    if (tid < 36) nv[tid] = numnav[b*NAV_ + tid];
    __syncthreads();
    if (tid == 0) {
        float m = nv[0];
        for (int i = 1; i < 36; ++i) m = fmaxf(m, nv[i]);
        float s = 0.f;
        for (int i = 0; i < 36; ++i) s += expf(nv[i]-m);
        nms[0] = m; nms[1] = s;
    }
    __syncthreads();
    if (tid < 36) ws[WS_NAV + b*NAV_ + tid] = expf(nv[tid]-nms[0]) / nms[1];
}

// ---------------------------------------------------------------------------
// Kernel 1: FUSED conv1 + dyn conv -> canvas (f16); 5-band loop per block
// with async-STAGE (R14 geometry — best measured).  grid (2, 576).
// ---------------------------------------------------------------------------
__global__ __launch_bounds__(256)
void k_fused(const float* __restrict__ d0, const float* __restrict__ d1,
             const float* __restrict__ obj, const float* __restrict__ conv1_w,
             const float* __restrict__ conv1_b, float* __restrict__ ws)
{
    const int tid = threadIdx.x;
    const int half = blockIdx.x;      // 0..1
    const int plane = blockIdx.y;     // 0..575
    const int b = plane / NAV_;
    const int g = plane % NAV_;
    const int r0base = half * 5 * OUT_H;

    __shared__ __align__(16) unsigned char smem[2*INCH + OBJ_ROWS*ROWB + TD_ROWS*ROWB + 256];
    unsigned char* inL  = smem;
    unsigned char* objL = smem + 2*INCH;
    unsigned char* tdL  = objL + OBJ_ROWS*ROWB;
    u32* wts = (u32*)(tdL + TD_ROWS*ROWB);
    // wts[0..29] conv1 pairs | wts[32..61] kern pairs | f[62]=bias | f[63]=nav

    if (tid < 30) {
        const int ch = tid/15, ky = (tid%15)/3, k = tid%3;
        const float* wsrc = conv1_w + g*50 + ch*25 + ky*5;
        wts[tid] = pkh(wsrc[2*k], (k < 2) ? wsrc[2*k+1] : 0.f);
    } else if (tid >= 32 && tid < 62) {
        const int t2 = tid - 32;
        const int ch = t2/15, ky = (t2%15)/3, k = t2%3;
        const float* wsrc = ws + WS_KERN + plane*50 + ch*25 + ky*5;
        wts[tid] = pkh(wsrc[2*k], (k < 2) ? wsrc[2*k+1] : 0.f);
    } else if (tid == 62) ((float*)wts)[62] = conv1_b[g];
    else if (tid == 63)   ((float*)wts)[63] = ws[WS_NAV + plane];
    if (tid >= 64 && tid < 96) {
        const int t2 = tid - 64;
        const int rr = t2 >> 1;
        *(u32*)(tdL + rr*ROWB + ((t2 & 1) ? 324 : 0)) = 0;
    }

    const float* pd0 = d0 + (size_t)plane*PLANE_PX;
    const float* pd1 = d1 + (size_t)plane*PLANE_PX;
    const float* pob = obj + (size_t)plane*PLANE_PX;

    u32 meta[SPT];
    #pragma unroll
    for (int k = 0; k < SPT; ++k) {
        const int slot = tid + 256*k;
        u32 m = 0;
        if (slot < NSLOT) {
            int j, rr4, ss; u32 dst;
            if (slot < 2*IN_ROWS*44) {
                const int ch = slot / (IN_ROWS*44);
                const int rem = slot % (IN_ROWS*44);
                const int row = rem / 44;
                j = rem % 44; rr4 = row; ss = ch;
                dst = (u32)(ch*INCH + row*ROWB + j*8);
            } else {
                const int s2 = slot - 2*IN_ROWS*44;
                const int row = s2 / 44;
                j = s2 % 44; rr4 = row + 2; ss = 2;
                dst = (u32)(2*INCH + row*ROWB + j*8);
            }
            m = dst | ((u32)j << 15) | ((u32)rr4 << 21) | ((u32)ss << 26) | 0x80000000u;
        }
        meta[k] = m;
    }

    float4a pf[SPT];
    const float4a z4 = {0.f, 0.f, 0.f, 0.f};

    #define ISSUE(R0) {                                                        \
        _Pragma("unroll")                                                      \
        for (int k = 0; k < SPT; ++k) {                                        \
            float4a v = z4;                                                    \
            if (meta[k] & 0x80000000u) {                                       \
                const int j   = (int)((meta[k] >> 15) & 63u);                  \
                const int gr  = (R0) + (int)((meta[k] >> 21) & 31u) - 4;       \
                const int ss  = (int)((meta[k] >> 26) & 3u);                   \
                if ((unsigned)gr < (unsigned)H_ && j <= 40) {                  \
                    const float* src = (ss == 0) ? pd0 : ((ss == 1) ? pd1 : pob); \
                    const int co = (j == 0) ? 0 : ((j < 40) ? 4*j - 2 : 156);  \
                    v = *(const float4a*)(src + gr*W_ + co);                   \
                }                                                              \
            }                                                                  \
            pf[k] = v;                                                         \
        } }

    #define WRITEPF() {                                                        \
        _Pragma("unroll")                                                      \
        for (int k = 0; k < SPT; ++k) {                                        \
            if (meta[k] & 0x80000000u) {                                       \
                const int j = (int)((meta[k] >> 15) & 63u);                    \
                u32 lo = 0, hi = 0;                                            \
                if (j == 0)       { hi = pkh(pf[k].x, pf[k].y); }              \
                else if (j < 40)  { lo = pkh(pf[k].x, pf[k].y); hi = pkh(pf[k].z, pf[k].w); } \
                else if (j == 40) { lo = pkh(pf[k].z, pf[k].w); }              \
                *(int2*)(smem + (meta[k] & 0x7FFFu)) = make_int2((int)lo, (int)hi); \
            }                                                                  \
        } }

    // prologue: stage band 0
    ISSUE(r0base)
    WRITEPF()
    __syncthreads();

    for (int band = 0; band < 5; ++band) {
        const int r0 = r0base + band*OUT_H;
        if (band < 4) ISSUE(r0 + OUT_H)

        // ---- phase 1: td rows r0-2..r0+13 (16 x 20 tasks) -> tdL (f16)
        for (int t = tid; t < TD_ROWS*20; t += 256) {
            const int tr = t/20, s = t%20;
            const int gr = r0 - 2 + tr;
            u32* rowp = (u32*)(tdL + tr*ROWB);
            if ((unsigned)gr >= (unsigned)H_) {
                rowp[4*s+1] = 0;
                *(int2*)(rowp + 4*s + 2) = make_int2(0, 0);
                rowp[4*s+4] = 0;
                continue;
            }
            float acc[8];
            #pragma unroll
            for (int p = 0; p < 8; ++p) acc[p] = 0.f;
            u32 ew[30];
            LOAD_EW(ew, wts)
            conv8(inL + tr*ROWB + s*16, inL + INCH + tr*ROWB + s*16, ew, acc);
            const float bias = ((const float*)wts)[62];
            const u32 p0 = pkh(acc[0]+bias, acc[1]+bias);
            const u32 p1 = pkh(acc[2]+bias, acc[3]+bias);
            const u32 p2 = pkh(acc[4]+bias, acc[5]+bias);
            const u32 p3 = pkh(acc[6]+bias, acc[7]+bias);
            rowp[4*s+1] = p0;
            *(int2*)(rowp + 4*s + 2) = make_int2((int)p1, (int)p2);
            rowp[4*s+4] = p3;
        }
        __syncthreads();

        // ---- phase 2: dyn conv (12 x 20 tasks) -> canvas (f16)
        if (tid < OUT_H*20) {
            const int yr = tid/20, s = tid%20;
            float acc[8];
            #pragma unroll
            for (int p = 0; p < 8; ++p) acc[p] = 0.f;
            u32 ew[30];
            LOAD_EW(ew, wts + 32)
            conv8(tdL + yr*ROWB + s*16, objL + yr*ROWB + s*16, ew, acc);
            const float a = ((const float*)wts)[63];
            const int rowblk = 2 - g/12;
            const int colblk = g % 12;
            u16* cb = (u16*)(ws + WS_CANVAS) + (size_t)b*CANVAS_PX
                    + (size_t)(rowblk*H_ + r0 + yr)*CANVAS_W + colblk*W_ + s*8;
            const u32 q0 = pkh(a*acc[0], a*acc[1]);
            const u32 q1 = pkh(a*acc[2], a*acc[3]);
            const u32 q2 = pkh(a*acc[4], a*acc[5]);
            const u32 q3 = pkh(a*acc[6], a*acc[7]);
            *(int4*)cb = make_int4((int)q0, (int)q1, (int)q2, (int)q3);
        }
        __syncthreads();

        if (band < 4) {
            WRITEPF()
            __syncthreads();
        }
    }
}

// ---------------------------------------------------------------------------
// Kernel 3: conv2_1 + avgpool3x3/3, BOTH versions per block.  Stage 11 f16
// canvas rows into LDS coalesced; scattered reads hit LDS.  grid (19, 16).
// ---------------------------------------------------------------------------
__global__ __launch_bounds__(256)
void k_conv2a(const float* __restrict__ w21p, const float* __restrict__ b21p,
              float* __restrict__ ws)
{
    const int a = blockIdx.x;      // 0..18 pool-row
    const int b = blockIdx.y;      // batch
    const int tid = threadIdx.x;

    __shared__ __align__(16) u16 cvh[11*CANVAS_W];   // 42240 B
    __shared__ float s1[2*801];
    __shared__ float swt[25];
    if (tid < 25) swt[tid] = w21p[tid];
    const float b21 = b21p[0];

    const u16* cvsrc = (const u16*)(ws + WS_CANVAS) + (size_t)b*CANVAS_PX;
    for (int i = tid; i < 11*240; i += 256) {
        const int k = i / 240;
        const int c8 = i % 240;
        *(int4*)&cvh[k*CANVAS_W + c8*8] =
            *(const int4*)(cvsrc + (size_t)(15*a + 5*k)*CANVAS_W + c8*8);
    }
    __syncthreads();

    for (int t = tid; t < 2*801; t += 256) {
        const int ver = t / 801;
        const int px = t % 801;
        const int row = px / 267;
        const int v = px % 267;
        const int coloff = ver ? (CANVAS_W - W_) : 0;
        float acc = b21;
        #pragma unroll
        for (int ky = 0; ky < 5; ++ky) {
            const u16* rp = &cvh[(row + 2*ky)*CANVAS_W];
            #pragma unroll
            for (int kx = 0; kx < 5; ++kx) {
                int c = 7*v + 10*kx + coloff;
                if (c >= CANVAS_W) c -= CANVAS_W;
                acc += swt[ky*5+kx] * h2f(rp[c]);
            }
        }
        s1[ver*801 + px] = acc;
    }
    __syncthreads();

    if (tid < 2*89) {
        const int ver = tid / 89;
        const int bb = tid % 89;
        float s = 0.f;
        #pragma unroll
        for (int i = 0; i < 3; ++i)
            #pragma unroll
            for (int j = 0; j < 3; ++j)
                s += s1[ver*801 + i*267 + 3*bb + j];
        ws[WS_POOL1 + ((b*2 + ver)*19 + a)*89 + bb] = s * (1.f/9.f);
    }
}

// ---------------------------------------------------------------------------
// Kernel 4: conv2_2 + avgpool(3,9)/3 + v2 roll + combine + flip + softmax/10
// + mask.  grid 16, 256 threads.
// ---------------------------------------------------------------------------
__global__ __launch_bounds__(256)
void k_conv2b(const float* __restrict__ w22p, const float* __restrict__ b22p,
              const int* __restrict__ navidx, float* __restrict__ ws,
              float* __restrict__ out)
{
    const int b = blockIdx.x;
    __shared__ float p[2*19*89];
    __shared__ float s2[2*9*43];
    __shared__ float svf[36];
    __shared__ float sms[2];
    __shared__ float swt[9];

    for (int i = threadIdx.x; i < 2*19*89; i += 256)
        p[i] = ws[WS_POOL1 + (b*2)*19*89 + i];
    if (threadIdx.x < 9) swt[threadIdx.x] = w22p[threadIdx.x];
    const float b22 = b22p[0];
    __syncthreads();

    for (int t = threadIdx.x; t < 2*9*43; t += 256) {
        const int ver = t / 387;
        const int r = t % 387;
        const int pp = r / 43;
        const int q = r % 43;
        float acc = b22;
        #pragma unroll
        for (int i = 0; i < 3; ++i)
            #pragma unroll
            for (int j = 0; j < 3; ++j)
                acc += swt[i*3+j] * p[(ver*19 + (2*pp+i))*89 + 2*q + 2*j];
        s2[ver*387 + pp*43 + q] = acc;
    }
    __syncthreads();

    if (threadIdx.x < 36) {
        const int gg = threadIdx.x;
        const int io = 2 - gg/12;
        const int j  = gg % 12;
        const int j2 = (j + 1) % 12;
        float s = 0.f;
        #pragma unroll
        for (int ii = 0; ii < 3; ++ii)
            #pragma unroll
            for (int jj = 0; jj < 9; ++jj)
                s += s2[(3*io+ii)*43 + 3*j + jj] + s2[387 + (3*io+ii)*43 + 3*j2 + jj];
        svf[gg] = s * (0.5f/27.f);
    }
    __syncthreads();
    if (threadIdx.x == 0) {
        float m = svf[0];
        for (int i = 1; i < 36; ++i) m = fmaxf(m, svf[i]);
        float s = 0.f;
        for (int i = 0; i < 36; ++i) s += expf((svf[i]-m)*0.1f);
        sms[0] = m; sms[1] = s;
    }
    __syncthreads();
    if (threadIdx.x < 36) {
        const float v = expf((svf[threadIdx.x]-sms[0])*0.1f) / sms[1];
        ws[WS_VF + b*36 + threadIdx.x] = v;
        out[16384 + b*36 + threadIdx.x] = v;
    }
    if (threadIdx.x < 37) {
        const int j = threadIdx.x;
        float v = (j == 0) ? 1.f : 0.f;
        #pragma unroll
        for (int t = 0; t < 8; ++t)
            if (navidx[b*8+t] + 1 == j) v = 1.f;
        out[16960 + b*37 + j] = v;
    }
}

// ---------------------------------------------------------------------------
// Kernel 5: LSTM GEMM + pointwise.  grid 256, 256 threads.  CT_STRIDE 17
// (odd -> conflict-free inner-loop LDS reads).
// ---------------------------------------------------------------------------
#define CT_STRIDE 17
__global__ __launch_bounds__(256)
void k_lstm(const float* __restrict__ wctx, const float* __restrict__ pre_action,
            const float* __restrict__ h0, const float* __restrict__ c0,
            const float* __restrict__ w_ih, const float* __restrict__ w_hh,
            const float* __restrict__ b_ih, const float* __restrict__ b_hh,
            const float* __restrict__ ws, float* __restrict__ out)
{
    __shared__ float cT[1096*CT_STRIDE];
    __shared__ float red[8*32*16];
    __shared__ float gatev[8][16];
    const int tid = threadIdx.x;

    for (int idx = tid; idx < 1096*16; idx += 256) {
        const int bb = idx / 1096;
        const int k = idx - bb*1096;
        float v;
        if (k < 512)       v = wctx[bb*512 + k];
        else if (k < 548)  v = ws[WS_VF + bb*36 + (k-512)];
        else if (k < 552)  v = ws[WS_FATT + bb*4 + (k-548)];
        else if (k < 584)  v = pre_action[bb*32 + (k-552)];
        else               v = h0[bb*512 + (k-584)];
        cT[k*CT_STRIDE + bb] = v;
    }
    __syncthreads();

    const int rl = tid >> 5;
    const int lane = tid & 31;
    const int u0 = blockIdx.x*2;
    const int ul = rl & 1;
    const int gate = rl >> 1;
    const int r = u0 + ul + gate*512;

    float acc[16];
    #pragma unroll
    for (int i = 0; i < 16; ++i) acc[i] = 0.f;

    const float* wih_r = w_ih + (size_t)r*584;
    for (int k = lane; k < 584; k += 32) {
        const float wv = wih_r[k];
        const float* cp = cT + k*CT_STRIDE;
        #pragma unroll
        for (int i = 0; i < 16; ++i) acc[i] += wv*cp[i];
    }
    const float* whh_r = w_hh + (size_t)r*512;
    for (int k = lane; k < 512; k += 32) {
        const float wv = whh_r[k];
        const float* cp = cT + (584+k)*CT_STRIDE;
        #pragma unroll
        for (int i = 0; i < 16; ++i) acc[i] += wv*cp[i];
    }
    float* rp = red + (rl*32 + lane)*16;
    #pragma unroll
    for (int i = 0; i < 16; ++i) rp[i] = acc[i];
    __syncthreads();

    if (tid < 128) {
        const int rr = tid >> 4;
        const int bb = tid & 15;
        const int rrow = u0 + (rr & 1) + (rr >> 1)*512;
        float s = b_ih[rrow] + b_hh[rrow];
        for (int l = 0; l < 32; ++l) s += red[(rr*32 + l)*16 + bb];
        gatev[rr][bb] = s;
    }
    __syncthreads();

    if (tid < 32) {
        const int ul2 = tid >> 4;
        const int bb = tid & 15;
        const int u = u0 + ul2;
        const float gi = gatev[0+ul2][bb];
        const float gf = gatev[2+ul2][bb];
        const float gg = gatev[4+ul2][bb];
        const float go = gatev[6+ul2][bb];
        const float c1 = sigmoidf_(gf)*c0[bb*512+u] + sigmoidf_(gi)*tanhf(gg);
        const float h1 = sigmoidf_(go)*tanhf(c1);
        out[bb*512 + u] = h1;
        out[8192 + bb*512 + u] = c1;
    }
}

// ---------------------------------------------------------------------------
extern "C" void kernel_launch(void* const* d_in, const int* in_sizes, int n_in,
                              void* d_out, int out_size, void* d_ws, size_t ws_size,
                              hipStream_t stream)
{
    const float* d0        = (const float*)d_in[0];
    const float* d1        = (const float*)d_in[1];
    const float* obj       = (const float*)d_in[2];
    const float* numnav    = (const float*)d_in[3];
    const float* preact    = (const float*)d_in[4];
    const float* h0        = (const float*)d_in[5];
    const float* c0        = (const float*)d_in[6];
    const float* wctx      = (const float*)d_in[7];
    const int*   navidx    = (const int*)d_in[8];
    const float* conv1_w   = (const float*)d_in[9];
    const float* conv1_b   = (const float*)d_in[10];
    const float* dynf      = (const float*)d_in[11];
    const float* dw1       = (const float*)d_in[12];
    const float* db1       = (const float*)d_in[13];
    const float* dw2       = (const float*)d_in[14];
    const float* db2       = (const float*)d_in[15];
    const float* w21       = (const float*)d_in[16];
    const float* b21       = (const float*)d_in[17];
    const float* w22       = (const float*)d_in[18];
    const float* b22       = (const float*)d_in[19];
    const float* wih       = (const float*)d_in[20];
    const float* whh       = (const float*)d_in[21];
    const float* bih       = (const float*)d_in[22];
    const float* bhh       = (const float*)d_in[23];
    float* ws  = (float*)d_ws;
    float* out = (float*)d_out;

    dim3 blk(256);
    k_pre   <<<dim3(16),      blk, 0, stream>>>(wctx, dw1, db1, dw2, db2, dynf, numnav, ws);
    k_fused <<<dim3(2, 576),  blk, 0, stream>>>(d0, d1, obj, conv1_w, conv1_b, ws);
    k_conv2a<<<dim3(19, 16),  blk, 0, stream>>>(w21, b21, ws);
    k_conv2b<<<dim3(16),      blk, 0, stream>>>(w22, b22, navidx, ws, out);
    k_lstm  <<<dim3(256),     blk, 0, stream>>>(wctx, preact, h0, c0, wih, whh,
                                                bih, bhh, ws, out);
}

// Round 20
// 137.103 us; speedup vs baseline: 1.1994x; 1.1994x over previous
//
#include <hip/hip_runtime.h>
#include <math.h>

#define B_ 16
#define NAV_ 36
#define H_ 120
#define W_ 160
#define HID_ 512
#define PLANES (B_*NAV_)          // 576
#define PLANE_PX (H_*W_)          // 19200
#define CANVAS_H 360
#define CANVAS_W 1920
#define CANVAS_PX (CANVAS_H*CANVAS_W)  // 691200

// fused f16 LDS tiling: 12 output rows/band, 5 bands per block (R14 geometry).
// ROWB = 400 B: multiple of 16 (keeps ds_read_b128 single-issue — ROWB=392
// split every odd-ky int4 read) AND 100 dwords ≡ 4 mod 32 (adjacent rows
// rotate across 4-bank clusters; measured 2.6x fewer conflict cycles than
// ROWB=352's 24-mod-32 stacking).
#define OUT_H 12
#define IN_ROWS 20
#define TD_ROWS 16
#define OBJ_ROWS 16
#define ROWB 400
#define INCH (IN_ROWS*ROWB)
#define NSLOT (2*IN_ROWS*44 + OBJ_ROWS*44)   // 2464
#define SPT 10

// workspace offsets (in floats); canvas region is used as f16 (half space)
#define WS_NAV    0
#define WS_FATT   576
#define WS_KERN   640
#define WS_TD     29440
#define WS_CANVAS (WS_TD + PLANES*PLANE_PX)
#define WS_POOL1  (WS_CANVAS + B_*CANVAS_PX)
#define WS_VF     (WS_POOL1 + B_*2*19*89)

typedef unsigned int u32;
typedef unsigned short u16;
typedef _Float16 h2_t __attribute__((ext_vector_type(2)));
typedef float float4a __attribute__((ext_vector_type(4), aligned(4)));

__device__ __forceinline__ float sigmoidf_(float x) { return 1.f / (1.f + expf(-x)); }

__device__ __forceinline__ u32 pkh(float a, float b) {
    return __builtin_bit_cast(u32, __builtin_amdgcn_cvt_pkrtz(a, b));
}
__device__ __forceinline__ float h2f(u16 h) {
    _Float16 v = __builtin_bit_cast(_Float16, h);
    return (float)v;
}
__device__ __forceinline__ float dot2h(u32 a, u32 b, float c) {
#if __has_builtin(__builtin_amdgcn_fdot2)
    return __builtin_amdgcn_fdot2(__builtin_bit_cast(h2_t, a),
                                  __builtin_bit_cast(h2_t, b), c, false);
#else
    float r;
    asm("v_dot2_f32_f16 %0, %1, %2, %3" : "=v"(r) : "v"(a), "v"(b), "v"(c));
    return r;
#endif
}

// 8-px, 2-channel, 5x5 conv via dot2 (odd pairs via alignbit).
__device__ __forceinline__ void conv8(const unsigned char* b0, const unsigned char* b1,
                                      const u32* ew, float* acc)
{
    #pragma unroll
    for (int ky = 0; ky < 5; ++ky) {
        const int off = ky*ROWB;
        int4 qa = *(const int4*)(b0 + off);
        int2 qb = *(const int2*)(b0 + off + 16);
        int4 ra = *(const int4*)(b1 + off);
        int2 rb = *(const int2*)(b1 + off + 16);
        u32 P[6] = {(u32)qa.x,(u32)qa.y,(u32)qa.z,(u32)qa.w,(u32)qb.x,(u32)qb.y};
        u32 Q[6] = {(u32)ra.x,(u32)ra.y,(u32)ra.z,(u32)ra.w,(u32)rb.x,(u32)rb.y};
        const u32 e0 = ew[ky*3+0], e1 = ew[ky*3+1], e2 = ew[ky*3+2];
        const u32 f0 = ew[15+ky*3+0], f1 = ew[15+ky*3+1], f2 = ew[15+ky*3+2];
        const u32 o0 = e0 << 16;
        const u32 o1 = __builtin_amdgcn_alignbit(e1, e0, 16);
        const u32 o2 = __builtin_amdgcn_alignbit(e2, e1, 16);
        const u32 g0 = f0 << 16;
        const u32 g1 = __builtin_amdgcn_alignbit(f1, f0, 16);
        const u32 g2 = __builtin_amdgcn_alignbit(f2, f1, 16);
        #pragma unroll
        for (int m = 0; m < 4; ++m) {
            acc[2*m]   = dot2h(e0, P[m], dot2h(e1, P[m+1], dot2h(e2, P[m+2], acc[2*m])));
            acc[2*m+1] = dot2h(o0, P[m], dot2h(o1, P[m+1], dot2h(o2, P[m+2], acc[2*m+1])));
            acc[2*m]   = dot2h(f0, Q[m], dot2h(f1, Q[m+1], dot2h(f2, Q[m+2], acc[2*m])));
            acc[2*m+1] = dot2h(g0, Q[m], dot2h(g1, Q[m+1], dot2h(g2, Q[m+2], acc[2*m+1])));
        }
    }
}

#define LOAD_EW(EW, SW)                                                        \
    {                                                                          \
        _Pragma("unroll")                                                      \
        for (int q = 0; q < 7; ++q) {                                          \
            int4 t_ = ((const int4*)(SW))[q];                                  \
            EW[4*q]=(u32)t_.x; EW[4*q+1]=(u32)t_.y; EW[4*q+2]=(u32)t_.z; EW[4*q+3]=(u32)t_.w; \
        }                                                                      \
        int2 t_ = ((const int2*)(SW))[14];                                     \
        EW[28]=(u32)t_.x; EW[29]=(u32)t_.y;                                    \
    }

// ---------------------------------------------------------------------------
// Kernel 0: tiny precompute.  grid 16, 256 threads.
// ---------------------------------------------------------------------------
__global__ __launch_bounds__(256)
void k_pre(const float* __restrict__ wctx, const float* __restrict__ dw1,
           const float* __restrict__ db1, const float* __restrict__ dw2,
           const float* __restrict__ db2, const float* __restrict__ dynf,
           const float* __restrict__ numnav, float* __restrict__ ws)
{
    const int tid = threadIdx.x;
    const int b = blockIdx.x;
    __shared__ float sh[128];
    __shared__ float sred[8];
    __shared__ float nv[36];
    __shared__ float nms[2];
    if (tid < 128) {
        float acc = db1[tid];
        for (int k = 0; k < HID_; ++k) acc += wctx[b*HID_ + k] * dw1[k*128 + tid];
        sh[tid] = fmaxf(acc, 0.f);
    }
    __syncthreads();
    if (tid < 4) {
        float acc = db2[tid];
        for (int j = 0; j < 128; ++j) acc += sh[j] * dw2[j*4 + tid];
        sred[tid] = acc;
    }
    __syncthreads();
    if (tid == 0) {
        float m = fmaxf(fmaxf(sred[0], sred[1]), fmaxf(sred[2], sred[3]));
        float e0 = expf(sred[0]-m), e1 = expf(sred[1]-m), e2 = expf(sred[2]-m), e3 = expf(sred[3]-m);
        float s = e0+e1+e2+e3;
        sred[4] = e0/s; sred[5] = e1/s; sred[6] = e2/s; sred[7] = e3/s;
        ws[WS_FATT + b*4+0] = sred[4]; ws[WS_FATT + b*4+1] = sred[5];
        ws[WS_FATT + b*4+2] = sred[6]; ws[WS_FATT + b*4+3] = sred[7];
    }
    __syncthreads();
    {
        const float fa0 = sred[4], fa1 = sred[5], fa2 = sred[6], fa3 = sred[7];
        for (int e = tid; e < 1800; e += 256) {
            float v = fa0*dynf[e] + fa1*dynf[1800+e] + fa2*dynf[3600+e] + fa3*dynf[5400+e];
            ws[WS_KERN + b*1800 + e] = v;
        }
    }
    if (tid < 36) nv[tid] = numnav[b*NAV_ + tid];
    __syncthreads();
    if (tid == 0) {
        float m = nv[0];
        for (int i = 1; i < 36; ++i) m = fmaxf(m, nv[i]);
        float s = 0.f;
        for (int i = 0; i < 36; ++i) s += expf(nv[i]-m);
        nms[0] = m; nms[1] = s;
    }
    __syncthreads();
    if (tid < 36) ws[WS_NAV + b*NAV_ + tid] = expf(nv[tid]-nms[0]) / nms[1];
}

// ---------------------------------------------------------------------------
// Kernel 1: FUSED conv1 + dyn conv -> canvas (f16); 5-band loop per block
// with async-STAGE (R14 geometry — best measured).  grid (2, 576).
// ---------------------------------------------------------------------------
__global__ __launch_bounds__(256)
void k_fused(const float* __restrict__ d0, const float* __restrict__ d1,
             const float* __restrict__ obj, const float* __restrict__ conv1_w,
             const float* __restrict__ conv1_b, float* __restrict__ ws)
{
    const int tid = threadIdx.x;
    const int half = blockIdx.x;      // 0..1
    const int plane = blockIdx.y;     // 0..575
    const int b = plane / NAV_;
    const int g = plane % NAV_;
    const int r0base = half * 5 * OUT_H;

    __shared__ __align__(16) unsigned char smem[2*INCH + OBJ_ROWS*ROWB + TD_ROWS*ROWB + 256];
    unsigned char* inL  = smem;
    unsigned char* objL = smem + 2*INCH;
    unsigned char* tdL  = objL + OBJ_ROWS*ROWB;
    u32* wts = (u32*)(tdL + TD_ROWS*ROWB);
    // wts[0..29] conv1 pairs | wts[32..61] kern pairs | f[62]=bias | f[63]=nav

    if (tid < 30) {
        const int ch = tid/15, ky = (tid%15)/3, k = tid%3;
        const float* wsrc = conv1_w + g*50 + ch*25 + ky*5;
        wts[tid] = pkh(wsrc[2*k], (k < 2) ? wsrc[2*k+1] : 0.f);
    } else if (tid >= 32 && tid < 62) {
        const int t2 = tid - 32;
        const int ch = t2/15, ky = (t2%15)/3, k = t2%3;
        const float* wsrc = ws + WS_KERN + plane*50 + ch*25 + ky*5;
        wts[tid] = pkh(wsrc[2*k], (k < 2) ? wsrc[2*k+1] : 0.f);
    } else if (tid == 62) ((float*)wts)[62] = conv1_b[g];
    else if (tid == 63)   ((float*)wts)[63] = ws[WS_NAV + plane];
    if (tid >= 64 && tid < 96) {
        const int t2 = tid - 64;
        const int rr = t2 >> 1;
        *(u32*)(tdL + rr*ROWB + ((t2 & 1) ? 324 : 0)) = 0;
    }

    const float* pd0 = d0 + (size_t)plane*PLANE_PX;
    const float* pd1 = d1 + (size_t)plane*PLANE_PX;
    const float* pob = obj + (size_t)plane*PLANE_PX;

    u32 meta[SPT];
    #pragma unroll
    for (int k = 0; k < SPT; ++k) {
        const int slot = tid + 256*k;
        u32 m = 0;
        if (slot < NSLOT) {
            int j, rr4, ss; u32 dst;
            if (slot < 2*IN_ROWS*44) {
                const int ch = slot / (IN_ROWS*44);
                const int rem = slot % (IN_ROWS*44);
                const int row = rem / 44;
                j = rem % 44; rr4 = row; ss = ch;
                dst = (u32)(ch*INCH + row*ROWB + j*8);
            } else {
                const int s2 = slot - 2*IN_ROWS*44;
                const int row = s2 / 44;
                j = s2 % 44; rr4 = row + 2; ss = 2;
                dst = (u32)(2*INCH + row*ROWB + j*8);
            }
            m = dst | ((u32)j << 15) | ((u32)rr4 << 21) | ((u32)ss << 26) | 0x80000000u;
        }
        meta[k] = m;
    }

    float4a pf[SPT];
    const float4a z4 = {0.f, 0.f, 0.f, 0.f};

    #define ISSUE(R0) {                                                        \
        _Pragma("unroll")                                                      \
        for (int k = 0; k < SPT; ++k) {                                        \
            float4a v = z4;                                                    \
            if (meta[k] & 0x80000000u) {                                       \
                const int j   = (int)((meta[k] >> 15) & 63u);                  \
                const int gr  = (R0) + (int)((meta[k] >> 21) & 31u) - 4;       \
                const int ss  = (int)((meta[k] >> 26) & 3u);                   \
                if ((unsigned)gr < (unsigned)H_ && j <= 40) {                  \
                    const float* src = (ss == 0) ? pd0 : ((ss == 1) ? pd1 : pob); \
                    const int co = (j == 0) ? 0 : ((j < 40) ? 4*j - 2 : 156);  \
                    v = *(const float4a*)(src + gr*W_ + co);                   \
                }                                                              \
            }                                                                  \
            pf[k] = v;                                                         \
        } }

    #define WRITEPF() {                                                        \
        _Pragma("unroll")                                                      \
        for (int k = 0; k < SPT; ++k) {                                        \
            if (meta[k] & 0x80000000u) {                                       \
                const int j = (int)((meta[k] >> 15) & 63u);                    \
                u32 lo = 0, hi = 0;                                            \
                if (j == 0)       { hi = pkh(pf[k].x, pf[k].y); }              \
                else if (j < 40)  { lo = pkh(pf[k].x, pf[k].y); hi = pkh(pf[k].z, pf[k].w); } \
                else if (j == 40) { lo = pkh(pf[k].z, pf[k].w); }              \
                *(int2*)(smem + (meta[k] & 0x7FFFu)) = make_int2((int)lo, (int)hi); \
            }                                                                  \
        } }

    // prologue: stage band 0
    ISSUE(r0base)
    WRITEPF()
    __syncthreads();

    for (int band = 0; band < 5; ++band) {
        const int r0 = r0base + band*OUT_H;
        if (band < 4) ISSUE(r0 + OUT_H)

        // ---- phase 1: td rows r0-2..r0+13 (16 x 20 tasks) -> tdL (f16)
        for (int t = tid; t < TD_ROWS*20; t += 256) {
            const int tr = t/20, s = t%20;
            const int gr = r0 - 2 + tr;
            u32* rowp = (u32*)(tdL + tr*ROWB);
            if ((unsigned)gr >= (unsigned)H_) {
                rowp[4*s+1] = 0;
                *(int2*)(rowp + 4*s + 2) = make_int2(0, 0);
                rowp[4*s+4] = 0;
                continue;
            }
            float acc[8];
            #pragma unroll
            for (int p = 0; p < 8; ++p) acc[p] = 0.f;
            u32 ew[30];
            LOAD_EW(ew, wts)
            conv8(inL + tr*ROWB + s*16, inL + INCH + tr*ROWB + s*16, ew, acc);
            const float bias = ((const float*)wts)[62];
            const u32 p0 = pkh(acc[0]+bias, acc[1]+bias);
            const u32 p1 = pkh(acc[2]+bias, acc[3]+bias);
            const u32 p2 = pkh(acc[4]+bias, acc[5]+bias);
            const u32 p3 = pkh(acc[6]+bias, acc[7]+bias);
            rowp[4*s+1] = p0;
            *(int2*)(rowp + 4*s + 2) = make_int2((int)p1, (int)p2);
            rowp[4*s+4] = p3;
        }
        __syncthreads();

        // ---- phase 2: dyn conv (12 x 20 tasks) -> canvas (f16)
        if (tid < OUT_H*20) {
            const int yr = tid/20, s = tid%20;
            float acc[8];
            #pragma unroll
            for (int p = 0; p < 8; ++p) acc[p] = 0.f;
            u32 ew[30];
            LOAD_EW(ew, wts + 32)
            conv8(tdL + yr*ROWB + s*16, objL + yr*ROWB + s*16, ew, acc);
            const float a = ((const float*)wts)[63];
            const int rowblk = 2 - g/12;
            const int colblk = g % 12;
            u16* cb = (u16*)(ws + WS_CANVAS) + (size_t)b*CANVAS_PX
                    + (size_t)(rowblk*H_ + r0 + yr)*CANVAS_W + colblk*W_ + s*8;
            const u32 q0 = pkh(a*acc[0], a*acc[1]);
            const u32 q1 = pkh(a*acc[2], a*acc[3]);
            const u32 q2 = pkh(a*acc[4], a*acc[5]);
            const u32 q3 = pkh(a*acc[6], a*acc[7]);
            *(int4*)cb = make_int4((int)q0, (int)q1, (int)q2, (int)q3);
        }
        __syncthreads();

        if (band < 4) {
            WRITEPF()
            __syncthreads();
        }
    }
}

// ---------------------------------------------------------------------------
// Kernel 3: conv2_1 + avgpool3x3/3, BOTH versions per block.  Stage 11 f16
// canvas rows into LDS coalesced; scattered reads hit LDS.  grid (19, 16).
// ---------------------------------------------------------------------------
__global__ __launch_bounds__(256)
void k_conv2a(const float* __restrict__ w21p, const float* __restrict__ b21p,
              float* __restrict__ ws)
{
    const int a = blockIdx.x;      // 0..18 pool-row
    const int b = blockIdx.y;      // batch
    const int tid = threadIdx.x;

    __shared__ __align__(16) u16 cvh[11*CANVAS_W];   // 42240 B
    __shared__ float s1[2*801];
    __shared__ float swt[25];
    if (tid < 25) swt[tid] = w21p[tid];
    const float b21 = b21p[0];

    const u16* cvsrc = (const u16*)(ws + WS_CANVAS) + (size_t)b*CANVAS_PX;
    for (int i = tid; i < 11*240; i += 256) {
        const int k = i / 240;
        const int c8 = i % 240;
        *(int4*)&cvh[k*CANVAS_W + c8*8] =
            *(const int4*)(cvsrc + (size_t)(15*a + 5*k)*CANVAS_W + c8*8);
    }
    __syncthreads();

    for (int t = tid; t < 2*801; t += 256) {
        const int ver = t / 801;
        const int px = t % 801;
        const int row = px / 267;
        const int v = px % 267;
        const int coloff = ver ? (CANVAS_W - W_) : 0;
        float acc = b21;
        #pragma unroll
        for (int ky = 0; ky < 5; ++ky) {
            const u16* rp = &cvh[(row + 2*ky)*CANVAS_W];
            #pragma unroll
            for (int kx = 0; kx < 5; ++kx) {
                int c = 7*v + 10*kx + coloff;
                if (c >= CANVAS_W) c -= CANVAS_W;
                acc += swt[ky*5+kx] * h2f(rp[c]);
            }
        }
        s1[ver*801 + px] = acc;
    }
    __syncthreads();

    if (tid < 2*89) {
        const int ver = tid / 89;
        const int bb = tid % 89;
        float s = 0.f;
        #pragma unroll
        for (int i = 0; i < 3; ++i)
            #pragma unroll
            for (int j = 0; j < 3; ++j)
                s += s1[ver*801 + i*267 + 3*bb + j];
        ws[WS_POOL1 + ((b*2 + ver)*19 + a)*89 + bb] = s * (1.f/9.f);
    }
}

// ---------------------------------------------------------------------------
// Kernel 4: conv2_2 + avgpool(3,9)/3 + v2 roll + combine + flip + softmax/10
// + mask.  grid 16, 256 threads.
// ---------------------------------------------------------------------------
__global__ __launch_bounds__(256)
void k_conv2b(const float* __restrict__ w22p, const float* __restrict__ b22p,
              const int* __restrict__ navidx, float* __restrict__ ws,
              float* __restrict__ out)
{
    const int b = blockIdx.x;
    __shared__ float p[2*19*89];
    __shared__ float s2[2*9*43];
    __shared__ float svf[36];
    __shared__ float sms[2];
    __shared__ float swt[9];

    for (int i = threadIdx.x; i < 2*19*89; i += 256)
        p[i] = ws[WS_POOL1 + (b*2)*19*89 + i];
    if (threadIdx.x < 9) swt[threadIdx.x] = w22p[threadIdx.x];
    const float b22 = b22p[0];
    __syncthreads();

    for (int t = threadIdx.x; t < 2*9*43; t += 256) {
        const int ver = t / 387;
        const int r = t % 387;
        const int pp = r / 43;
        const int q = r % 43;
        float acc = b22;
        #pragma unroll
        for (int i = 0; i < 3; ++i)
            #pragma unroll
            for (int j = 0; j < 3; ++j)
                acc += swt[i*3+j] * p[(ver*19 + (2*pp+i))*89 + 2*q + 2*j];
        s2[ver*387 + pp*43 + q] = acc;
    }
    __syncthreads();

    if (threadIdx.x < 36) {
        const int gg = threadIdx.x;
        const int io = 2 - gg/12;
        const int j  = gg % 12;
        const int j2 = (j + 1) % 12;
        float s = 0.f;
        #pragma unroll
        for (int ii = 0; ii < 3; ++ii)
            #pragma unroll
            for (int jj = 0; jj < 9; ++jj)
                s += s2[(3*io+ii)*43 + 3*j + jj] + s2[387 + (3*io+ii)*43 + 3*j2 + jj];
        svf[gg] = s * (0.5f/27.f);
    }
    __syncthreads();
    if (threadIdx.x == 0) {
        float m = svf[0];
        for (int i = 1; i < 36; ++i) m = fmaxf(m, svf[i]);
        float s = 0.f;
        for (int i = 0; i < 36; ++i) s += expf((svf[i]-m)*0.1f);
        sms[0] = m; sms[1] = s;
    }
    __syncthreads();
    if (threadIdx.x < 36) {
        const float v = expf((svf[threadIdx.x]-sms[0])*0.1f) / sms[1];
        ws[WS_VF + b*36 + threadIdx.x] = v;
        out[16384 + b*36 + threadIdx.x] = v;
    }
    if (threadIdx.x < 37) {
        const int j = threadIdx.x;
        float v = (j == 0) ? 1.f : 0.f;
        #pragma unroll
        for (int t = 0; t < 8; ++t)
            if (navidx[b*8+t] + 1 == j) v = 1.f;
        out[16960 + b*37 + j] = v;
    }
}

// ---------------------------------------------------------------------------
// Kernel 5: LSTM GEMM + pointwise.  grid 256, 256 threads.  CT_STRIDE 17
// (odd -> conflict-free inner-loop LDS reads).
// ---------------------------------------------------------------------------
#define CT_STRIDE 17
__global__ __launch_bounds__(256)
void k_lstm(const float* __restrict__ wctx, const float* __restrict__ pre_action,
            const float* __restrict__ h0, const float* __restrict__ c0,
            const float* __restrict__ w_ih, const float* __restrict__ w_hh,
            const float* __restrict__ b_ih, const float* __restrict__ b_hh,
            const float* __restrict__ ws, float* __restrict__ out)
{
    __shared__ float cT[1096*CT_STRIDE];
    __shared__ float red[8*32*16];
    __shared__ float gatev[8][16];
    const int tid = threadIdx.x;

    for (int idx = tid; idx < 1096*16; idx += 256) {
        const int bb = idx / 1096;
        const int k = idx - bb*1096;
        float v;
        if (k < 512)       v = wctx[bb*512 + k];
        else if (k < 548)  v = ws[WS_VF + bb*36 + (k-512)];
        else if (k < 552)  v = ws[WS_FATT + bb*4 + (k-548)];
        else if (k < 584)  v = pre_action[bb*32 + (k-552)];
        else               v = h0[bb*512 + (k-584)];
        cT[k*CT_STRIDE + bb] = v;
    }
    __syncthreads();

    const int rl = tid >> 5;
    const int lane = tid & 31;
    const int u0 = blockIdx.x*2;
    const int ul = rl & 1;
    const int gate = rl >> 1;
    const int r = u0 + ul + gate*512;

    float acc[16];
    #pragma unroll
    for (int i = 0; i < 16; ++i) acc[i] = 0.f;

    const float* wih_r = w_ih + (size_t)r*584;
    for (int k = lane; k < 584; k += 32) {
        const float wv = wih_r[k];
        const float* cp = cT + k*CT_STRIDE;
        #pragma unroll
        for (int i = 0; i < 16; ++i) acc[i] += wv*cp[i];
    }
    const float* whh_r = w_hh + (size_t)r*512;
    for (int k = lane; k < 512; k += 32) {
        const float wv = whh_r[k];
        const float* cp = cT + (584+k)*CT_STRIDE;
        #pragma unroll
        for (int i = 0; i < 16; ++i) acc[i] += wv*cp[i];
    }
    float* rp = red + (rl*32 + lane)*16;
    #pragma unroll
    for (int i = 0; i < 16; ++i) rp[i] = acc[i];
    __syncthreads();

    if (tid < 128) {
        const int rr = tid >> 4;
        const int bb = tid & 15;
        const int rrow = u0 + (rr & 1) + (rr >> 1)*512;
        float s = b_ih[rrow] + b_hh[rrow];
        for (int l = 0; l < 32; ++l) s += red[(rr*32 + l)*16 + bb];
        gatev[rr][bb] = s;
    }
    __syncthreads();

    if (tid < 32) {
        const int ul2 = tid >> 4;
        const int bb = tid & 15;
        const int u = u0 + ul2;
        const float gi = gatev[0+ul2][bb];
        const float gf = gatev[2+ul2][bb];
        const float gg = gatev[4+ul2][bb];
        const float go = gatev[6+ul2][bb];
        const float c1 = sigmoidf_(gf)*c0[bb*512+u] + sigmoidf_(gi)*tanhf(gg);
        const float h1 = sigmoidf_(go)*tanhf(c1);
        out[bb*512 + u] = h1;
        out[8192 + bb*512 + u] = c1;
    }
}

// ---------------------------------------------------------------------------
extern "C" void kernel_launch(void* const* d_in, const int* in_sizes, int n_in,
                              void* d_out, int out_size, void* d_ws, size_t ws_size,
                              hipStream_t stream)
{
    const float* d0        = (const float*)d_in[0];
    const float* d1        = (const float*)d_in[1];
    const float* obj       = (const float*)d_in[2];
    const float* numnav    = (const float*)d_in[3];
    const float* preact    = (const float*)d_in[4];
    const float* h0        = (const float*)d_in[5];
    const float* c0        = (const float*)d_in[6];
    const float* wctx      = (const float*)d_in[7];
    const int*   navidx    = (const int*)d_in[8];
    const float* conv1_w   = (const float*)d_in[9];
    const float* conv1_b   = (const float*)d_in[10];
    const float* dynf      = (const float*)d_in[11];
    const float* dw1       = (const float*)d_in[12];
    const float* db1       = (const float*)d_in[13];
    const float* dw2       = (const float*)d_in[14];
    const float* db2       = (const float*)d_in[15];
    const float* w21       = (const float*)d_in[16];
    const float* b21       = (const float*)d_in[17];
    const float* w22       = (const float*)d_in[18];
    const float* b22       = (const float*)d_in[19];
    const float* wih       = (const float*)d_in[20];
    const float* whh       = (const float*)d_in[21];
    const float* bih       = (const float*)d_in[22];
    const float* bhh       = (const float*)d_in[23];
    float* ws  = (float*)d_ws;
    float* out = (float*)d_out;

    dim3 blk(256);
    k_pre   <<<dim3(16),      blk, 0, stream>>>(wctx, dw1, db1, dw2, db2, dynf, numnav, ws);
    k_fused <<<dim3(2, 576),  blk, 0, stream>>>(d0, d1, obj, conv1_w, conv1_b, ws);
    k_conv2a<<<dim3(19, 16),  blk, 0, stream>>>(w21, b21, ws);
    k_conv2b<<<dim3(16),      blk, 0, stream>>>(w22, b22, navidx, ws, out);
    k_lstm  <<<dim3(256),     blk, 0, stream>>>(wctx, preact, h0, c0, wih, whh,
                                                bih, bhh, ws, out);
}